// Round 7
// baseline (821.209 us; speedup 1.0000x reference)
//
#include <hip/hip_runtime.h>
#include <math.h>
#include <stdint.h>

#define N_TOKENS 16384
#define D_MODEL  4096
#define N_EXP    64

#define T_PER 16                 // tokens per block (= tokens per wave)
#define NKS   4                  // k-slices = waves per block
#define KSL   (D_MODEL / NKS)    // 1024 k per wave
#define NG    (KSL / 8)          // 128 groups of 8 k
#define NBLK  (N_TOKENS / T_PER) // 1024 blocks -> 4 blocks/CU -> 4 waves/SIMD

// ---------------------------------------------------------------------------
// Pre-pass: w[64][4096] -> wf[k4][e][4] (k4 = k/4), so that a wave with
// lane = expert reads group k4 as one contiguous, coalesced 1 KB line
// (lane e -> 16 B float4 of its expert's 4 consecutive k). LDS transpose,
// coalesced on both sides. 1 MB total, L2-resident for the main kernel.
// ---------------------------------------------------------------------------
__global__ void __launch_bounds__(256)
w_to_frags(const float* __restrict__ w, float* __restrict__ wfr) {
    __shared__ float t[64][65];              // [k-local][expert], +1 pad
    const int k0 = blockIdx.x * 64;
    const int kc = (threadIdx.x & 15) * 4;
    const int e0 = threadIdx.x >> 4;         // 0..15
#pragma unroll
    for (int p = 0; p < 4; ++p) {
        int e = p * 16 + e0;
        float4 v = *(const float4*)(w + (size_t)e * D_MODEL + k0 + kc);
        t[kc + 0][e] = v.x; t[kc + 1][e] = v.y;
        t[kc + 2][e] = v.z; t[kc + 3][e] = v.w;
    }
    __syncthreads();
    const int e = threadIdx.x & 63;
    const int q = threadIdx.x >> 6;          // 0..3
#pragma unroll
    for (int i = 0; i < 4; ++i) {
        int k4l = q * 4 + i;                 // 0..15
        float4 v = make_float4(t[k4l * 4 + 0][e], t[k4l * 4 + 1][e],
                               t[k4l * 4 + 2][e], t[k4l * 4 + 3][e]);
        *(float4*)(wfr + ((size_t)(k0 / 4 + k4l) * 64 + e) * 4) = v;
    }
}

// ---------------------------------------------------------------------------
// Fused router, LDS-free inner loop.
// Block = 16 tokens, 256 threads = 4 waves; wave wv = k-slice wv (1024 k).
// lane = expert. Inner loop per 8-k group:
//   - w: 2x global_load_dwordx4 from wf, coalesced 1 KB/instr, L2-hot
//   - x: WAVE-UNIFORM scalar loads (lane doesn't appear in the address ->
//     s_load into SGPRs, hardware broadcast; no LDS staging, no barriers)
//   - 128 v_fmac_f32 (16 tokens x 8 k) -> ~90% of issue slots are FMA.
// ROUND-6 BUG FIX: wbase k4-term was missing the *4 element width
// (ksu*16384 instead of ksu*65536) -> waves 1-3 read wrong w fragments ->
// wrong logits for 3/4 of the k-reduction -> scrambled top-k indices.
// Layout math: float offset of (k4=K, e) = (K*64 + e)*4.
// Epilogue: 16 KB LDS k-reduce (4 slices), softmax/top2 with ballot-argmax
// (ties -> lowest index, matching jax.lax.top_k), per-block p/f sums.
// ---------------------------------------------------------------------------
__global__ void __launch_bounds__(256)
router_fused(const float* __restrict__ x, const float* __restrict__ wfr,
             float* __restrict__ out, float* __restrict__ block_sums) {
    __shared__ float part[NKS * T_PER * N_EXP];   // 4096 floats = 16 KB
    __shared__ float pf[2 * NKS * N_EXP];         // 512 floats

    const int tid  = threadIdx.x;
    const int wv   = tid >> 6;               // k-slice index
    const int lane = tid & 63;               // expert index
    const int tok0 = blockIdx.x * T_PER;

    const int ksu = __builtin_amdgcn_readfirstlane(wv);
    const float* xbase = x + (size_t)tok0 * D_MODEL + (size_t)ksu * KSL;
    // wave's first k4 line = ksu * (KSL/4); each line is 64 experts * 4 floats
    const float* wbase = wfr + ((size_t)ksu * (KSL / 4) * 64 + lane) * 4;

    float acc[T_PER] = {};

    // prefetch w group 0 (two 1 KB lines: k4 = 2g, 2g+1)
    float4 w0 = *(const float4*)(wbase);
    float4 w1 = *(const float4*)(wbase + 256);

    for (int g = 0; g < NG; ++g) {
        float4 c0 = w0, c1 = w1;
        if (g + 1 < NG) {
            const float* nw = wbase + (size_t)(g + 1) * 512;
            w0 = *(const float4*)(nw);
            w1 = *(const float4*)(nw + 256);
        }
        const float* xg = xbase + g * 8;     // wave-uniform pointer
#pragma unroll
        for (int t = 0; t < T_PER; ++t) {
            const float* xr = xg + (size_t)t * D_MODEL;   // uniform -> s_load
            float a = acc[t];
            a = fmaf(xr[0], c0.x, a);
            a = fmaf(xr[1], c0.y, a);
            a = fmaf(xr[2], c0.z, a);
            a = fmaf(xr[3], c0.w, a);
            a = fmaf(xr[4], c1.x, a);
            a = fmaf(xr[5], c1.y, a);
            a = fmaf(xr[6], c1.z, a);
            a = fmaf(xr[7], c1.w, a);
            acc[t] = a;
        }
    }

    // ---- epilogue: k-slice reduce + softmax/top2 ----
#pragma unroll
    for (int t = 0; t < T_PER; ++t)
        part[(wv * T_PER + t) * N_EXP + lane] = acc[t];
    __syncthreads();

    float p_acc = 0.f, f_acc = 0.f;          // lane = expert
#pragma unroll 1
    for (int it = 0; it < 4; ++it) {
        const int tl = it * 4 + wv;          // local token, 4 waves x 4
        float logit = part[(0 * T_PER + tl) * N_EXP + lane]
                    + part[(1 * T_PER + tl) * N_EXP + lane]
                    + part[(2 * T_PER + tl) * N_EXP + lane]
                    + part[(3 * T_PER + tl) * N_EXP + lane];

        // top-1: value max-reduce, then ballot -> lowest tied index
        float m = logit;
#pragma unroll
        for (int off = 32; off; off >>= 1)
            m = fmaxf(m, __shfl_xor(m, off, 64));
        unsigned long long b1 = __ballot(logit == m);
        int i1 = __ffsll(b1) - 1;

        float p = expf(logit - m);
        float denom = p;
#pragma unroll
        for (int off = 32; off; off >>= 1)
            denom += __shfl_xor(denom, off, 64);

        p_acc += p / denom;                  // router_probs[token][lane]
        if (lane == i1) f_acc += 1.f;

        // top-2: mask i1, repeat
        float lx = (lane == i1) ? -__builtin_inff() : logit;
        float m2 = lx;
#pragma unroll
        for (int off = 32; off; off >>= 1)
            m2 = fmaxf(m2, __shfl_xor(m2, off, 64));
        unsigned long long b2 = __ballot(lx == m2);
        int i2 = __ffsll(b2) - 1;

        if (lane == 0) {
            float p1 = 1.0f / denom;                 // exp(m-m)/denom
            float p2 = expf(m2 - m) / denom;
            float s12 = p1 + p2;
            int token = tok0 + tl;
            ((float2*)out)[token] = make_float2(p1 / s12, p2 / s12);
            ((float2*)(out + 2 * N_TOKENS))[token] =
                make_float2((float)i1, (float)i2);
        }
    }

    // block-level p/f sums -> block_sums (no atomics)
    pf[wv * 64 + lane]       = p_acc;
    pf[256 + wv * 64 + lane] = f_acc;
    __syncthreads();
    if (tid < N_EXP) {
        float ps = pf[tid] + pf[64 + tid] + pf[128 + tid] + pf[192 + tid];
        float fs = pf[256 + tid] + pf[320 + tid] + pf[384 + tid] + pf[448 + tid];
        block_sums[(size_t)blockIdx.x * 128 + tid]      = ps;
        block_sums[(size_t)blockIdx.x * 128 + 64 + tid] = fs;
    }
}

// ---------------------------------------------------------------------------
// Final: reduce 1024 blocks' p/f sums, loss = 0.01 * sum_e (f_e/N)*(p_e/N).
// ---------------------------------------------------------------------------
__global__ void __launch_bounds__(256)
router_final(const float* __restrict__ block_sums, float* __restrict__ out) {
    __shared__ float sp[4][N_EXP];
    __shared__ float sf[4][N_EXP];

    int tid  = threadIdx.x;
    int wv   = tid >> 6;
    int lane = tid & 63;

    float ps = 0.f, fs = 0.f;
#pragma unroll 8
    for (int b = wv * (NBLK / 4); b < (wv + 1) * (NBLK / 4); ++b) {
        ps += block_sums[(size_t)b * 128 + lane];
        fs += block_sums[(size_t)b * 128 + 64 + lane];
    }
    sp[wv][lane] = ps;
    sf[wv][lane] = fs;
    __syncthreads();

    if (tid < N_EXP) {
        float pt = sp[0][tid] + sp[1][tid] + sp[2][tid] + sp[3][tid];
        float ft = sf[0][tid] + sf[1][tid] + sf[2][tid] + sf[3][tid];
        float v = pt * ft;
#pragma unroll
        for (int off = 1; off < 64; off <<= 1)
            v += __shfl_xor(v, off, 64);
        if (tid == 0)
            out[4 * N_TOKENS] = 0.01f * v / ((float)N_TOKENS * (float)N_TOKENS);
    }
}

// ---------------------------------------------------------------------------
extern "C" void kernel_launch(void* const* d_in, const int* in_sizes, int n_in,
                              void* d_out, int out_size, void* d_ws, size_t ws_size,
                              hipStream_t stream) {
    (void)in_sizes; (void)n_in; (void)out_size; (void)ws_size;
    const float* x = (const float*)d_in[0];
    const float* w = (const float*)d_in[1];
    float* out = (float*)d_out;

    float* wF = (float*)d_ws;                            // 4096*64*4 = 1 MB
    float* block_sums = wF + (size_t)D_MODEL * N_EXP;    // 1024*128*4 = 512 KB

    w_to_frags<<<D_MODEL / 64, 256, 0, stream>>>(w, wF);
    router_fused<<<NBLK, 256, 0, stream>>>(x, wF, out, block_sums);
    router_final<<<1, 256, 0, stream>>>(block_sums, out);
}

// Round 8
// 419.207 us; speedup vs baseline: 1.9590x; 1.9590x over previous
//
#include <hip/hip_runtime.h>
#include <math.h>

#define N_TOKENS 16384
#define D_MODEL  4096
#define N_EXP    64

#define TOKB  64                 // tokens per block (lane = token)
#define NWV   16                 // waves per block (1024 threads)
#define NSL   8                  // k-slices
#define KSL   (D_MODEL / NSL)    // 512 k per wave
#define CH    16                 // k per chunk (= 64 B per-lane line)
#define NCH   (KSL / CH)         // 32 chunks
#define PPAD  36                 // partial-tile expert stride (conflict-free)
#define PFOFF (NWV * TOKB * PPAD) // 36864 floats
#define NBLK  (N_TOKENS / TOKB)  // 256 blocks = 1/CU -> 16 waves/CU = 4/SIMD

// ---------------------------------------------------------------------------
// Pre-pass: w[64][4096] -> wT[4096][64] (k-major). A k-row's 64 experts are
// contiguous -> per-k expert-half = 32 uniform floats = 2x s_load_dwordx16.
// ---------------------------------------------------------------------------
__global__ void __launch_bounds__(256)
transpose_w(const float* __restrict__ w, float* __restrict__ wt) {
    __shared__ float t[64][65];
    const int k0 = blockIdx.x * 64;
    const int kc = (threadIdx.x & 15) * 4;
    const int e0 = threadIdx.x >> 4;         // 0..15
#pragma unroll
    for (int p = 0; p < 4; ++p) {
        int e = p * 16 + e0;
        float4 v = *(const float4*)(w + (size_t)e * D_MODEL + k0 + kc);
        t[kc + 0][e] = v.x; t[kc + 1][e] = v.y;
        t[kc + 2][e] = v.z; t[kc + 3][e] = v.w;
    }
    __syncthreads();
    const int kr = threadIdx.x >> 2;         // 0..63
    const int ec = (threadIdx.x & 3) * 16;
#pragma unroll
    for (int j = 0; j < 4; ++j) {
        float4 v = make_float4(t[kr][ec + j * 4 + 0], t[kr][ec + j * 4 + 1],
                               t[kr][ec + j * 4 + 2], t[kr][ec + j * 4 + 3]);
        *(float4*)(wt + (size_t)(k0 + kr) * N_EXP + ec + j * 4) = v;
    }
}

// ---------------------------------------------------------------------------
// Fused router — lane = TOKEN, experts in SGPRs (round 7 inverted).
// Block = 64 tokens, 1024 threads = 16 waves. Wave wid = (half h = wid&1,
// k-slice s = wid>>1): acc[32] = 32 experts x 64 tokens over 512 k.
//   - x: per-lane global_load_dwordx4 x4 per 16-k chunk = exactly one 64B
//     line per thread, double-buffered in regs. Big array -> vector path.
//   - w: per k-row, 32 UNIFORM floats (wT row + h*32) -> compiler emits
//     s_load from L2-hot 1 MB wT; ~200cy latency hidden by 64cy FMA x 4
//     waves/SIMD. Small reused array -> scalar path. (Round 7 did the
//     reverse: 256 MB x through serial s_load at HBM latency = 22% VALU.)
//   - inner: 32 x v_fmac_f32 v_acc, s_w, v_x (1 SGPR read/instr). No LDS,
//     no barriers in the main loop.
// Epilogue: 16 partial tiles [64 tok][32 exp] in LDS (stride 36), 8-slice
// reduce, ballot-argmax softmax/top-2 (ties -> lowest index), p/f sums.
// ---------------------------------------------------------------------------
__global__ void __launch_bounds__(1024)
router_fused(const float* __restrict__ x, const float* __restrict__ wt,
             float* __restrict__ out, float* __restrict__ block_sums) {
    __shared__ float part[PFOFF + 2 * NWV * 64];   // 147456 + 8192 B

    const int tid  = threadIdx.x;
    const int wid  = tid >> 6;
    const int lane = tid & 63;               // token within block
    const int tok0 = blockIdx.x * TOKB;

    const int wid_u = __builtin_amdgcn_readfirstlane(wid);
    const int h = wid_u & 1;                 // expert half: experts h*32..+31
    const int s = wid_u >> 1;                // k-slice: k in [s*512, s*512+512)

    const float* xr = x + (size_t)(tok0 + lane) * D_MODEL + s * KSL;
    const float* wr = wt + (size_t)s * KSL * N_EXP + h * 32;   // uniform

    float acc[32] = {};

    float4 xa0 = *(const float4*)(xr + 0);
    float4 xa1 = *(const float4*)(xr + 4);
    float4 xa2 = *(const float4*)(xr + 8);
    float4 xa3 = *(const float4*)(xr + 12);

#pragma unroll 1
    for (int g = 0; g < NCH; ++g) {
        float4 xb0, xb1, xb2, xb3;
        if (g + 1 < NCH) {
            const float* xn = xr + (g + 1) * CH;
            xb0 = *(const float4*)(xn + 0);
            xb1 = *(const float4*)(xn + 4);
            xb2 = *(const float4*)(xn + 8);
            xb3 = *(const float4*)(xn + 12);
        }
        const float xc[CH] = {xa0.x, xa0.y, xa0.z, xa0.w,
                              xa1.x, xa1.y, xa1.z, xa1.w,
                              xa2.x, xa2.y, xa2.z, xa2.w,
                              xa3.x, xa3.y, xa3.z, xa3.w};
        const float* wg = wr + (size_t)g * CH * N_EXP;
#pragma unroll
        for (int k = 0; k < CH; ++k) {
            const float* wk = wg + k * N_EXP;      // uniform -> s_load
            const float xk = xc[k];
#pragma unroll
            for (int e = 0; e < 32; ++e)
                acc[e] = fmaf(wk[e], xk, acc[e]);
        }
        xa0 = xb0; xa1 = xb1; xa2 = xb2; xa3 = xb3;
    }

    // ---- epilogue: k-slice reduce + softmax/top2 ----
    {
        float* tp = part + (size_t)(wid * TOKB + lane) * PPAD;
#pragma unroll
        for (int e0 = 0; e0 < 32; e0 += 4)
            *(float4*)(tp + e0) = make_float4(acc[e0], acc[e0 + 1],
                                              acc[e0 + 2], acc[e0 + 3]);
    }
    __syncthreads();

    float p_acc = 0.f, f_acc = 0.f;          // lane = expert now
    const int he = lane >> 5;                // this expert's half
    const int ew = lane & 31;
#pragma unroll 1
    for (int it = 0; it < 4; ++it) {
        const int tl = wid * 4 + it;         // local token (16 waves x 4)
        float logit = 0.f;
#pragma unroll
        for (int sl = 0; sl < NSL; ++sl)
            logit += part[(size_t)((2 * sl + he) * TOKB + tl) * PPAD + ew];

        // top-1: value max-reduce, then ballot -> lowest tied index
        float m = logit;
#pragma unroll
        for (int off = 32; off; off >>= 1)
            m = fmaxf(m, __shfl_xor(m, off, 64));
        unsigned long long b1 = __ballot(logit == m);
        int i1 = __ffsll(b1) - 1;

        float p = expf(logit - m);
        float denom = p;
#pragma unroll
        for (int off = 32; off; off >>= 1)
            denom += __shfl_xor(denom, off, 64);

        p_acc += p / denom;                  // router_probs[token][lane]
        if (lane == i1) f_acc += 1.f;

        // top-2: mask i1, repeat
        float lx = (lane == i1) ? -__builtin_inff() : logit;
        float m2 = lx;
#pragma unroll
        for (int off = 32; off; off >>= 1)
            m2 = fmaxf(m2, __shfl_xor(m2, off, 64));
        unsigned long long b2 = __ballot(lx == m2);
        int i2 = __ffsll(b2) - 1;

        if (lane == 0) {
            float p1 = 1.0f / denom;                 // exp(m-m)/denom
            float p2 = expf(m2 - m) / denom;
            float s12 = p1 + p2;
            int token = tok0 + tl;
            ((float2*)out)[token] = make_float2(p1 / s12, p2 / s12);
            ((float2*)(out + 2 * N_TOKENS))[token] =
                make_float2((float)i1, (float)i2);
        }
    }

    // block-level p/f sums -> block_sums (no atomics)
    float* pf = part + PFOFF;                // [0,1024): p, [1024,2048): f
    pf[wid * 64 + lane]        = p_acc;
    pf[1024 + wid * 64 + lane] = f_acc;
    __syncthreads();
    if (tid < N_EXP) {
        float ps = 0.f, fs = 0.f;
#pragma unroll
        for (int hh = 0; hh < NWV; ++hh) {
            ps += pf[hh * 64 + tid];
            fs += pf[1024 + hh * 64 + tid];
        }
        block_sums[(size_t)blockIdx.x * 128 + tid]      = ps;
        block_sums[(size_t)blockIdx.x * 128 + 64 + tid] = fs;
    }
}

// ---------------------------------------------------------------------------
// Final: reduce 256 blocks' p/f sums, loss = 0.01 * sum_e (f_e/N)*(p_e/N).
// ---------------------------------------------------------------------------
__global__ void __launch_bounds__(256)
router_final(const float* __restrict__ block_sums, float* __restrict__ out) {
    __shared__ float sp[4][N_EXP];
    __shared__ float sf[4][N_EXP];

    int tid  = threadIdx.x;
    int wv   = tid >> 6;
    int lane = tid & 63;

    float ps = 0.f, fs = 0.f;
#pragma unroll 8
    for (int b = wv * (NBLK / 4); b < (wv + 1) * (NBLK / 4); ++b) {
        ps += block_sums[(size_t)b * 128 + lane];
        fs += block_sums[(size_t)b * 128 + 64 + lane];
    }
    sp[wv][lane] = ps;
    sf[wv][lane] = fs;
    __syncthreads();

    if (tid < N_EXP) {
        float pt = sp[0][tid] + sp[1][tid] + sp[2][tid] + sp[3][tid];
        float ft = sf[0][tid] + sf[1][tid] + sf[2][tid] + sf[3][tid];
        float v = pt * ft;
#pragma unroll
        for (int off = 1; off < 64; off <<= 1)
            v += __shfl_xor(v, off, 64);
        if (tid == 0)
            out[4 * N_TOKENS] = 0.01f * v / ((float)N_TOKENS * (float)N_TOKENS);
    }
}

// ---------------------------------------------------------------------------
extern "C" void kernel_launch(void* const* d_in, const int* in_sizes, int n_in,
                              void* d_out, int out_size, void* d_ws, size_t ws_size,
                              hipStream_t stream) {
    (void)in_sizes; (void)n_in; (void)out_size; (void)ws_size;
    const float* x = (const float*)d_in[0];
    const float* w = (const float*)d_in[1];
    float* out = (float*)d_out;

    float* wT = (float*)d_ws;                            // 4096*64*4 = 1 MB
    float* block_sums = wT + (size_t)D_MODEL * N_EXP;    // 256*128*4 = 128 KB

    transpose_w<<<D_MODEL / 64, 256, 0, stream>>>(w, wT);
    router_fused<<<NBLK, 1024, 0, stream>>>(x, wT, out, block_sums);
    router_final<<<1, 256, 0, stream>>>(block_sums, out);
}